// Round 11
// baseline (117.272 us; speedup 1.0000x reference)
//
#include <hip/hip_runtime.h>
#include <hip/hip_bf16.h>
#include <stdint.h>

#define B_    4
#define N_    8192
#define K_    32
#define CX    67      // 3 + C_IN
#define CMID  64
#define COUT  128

#define CSTR  104     // Xs k-row stride (elems): 208B rows -> every row 16B-aligned (b128 reads)
#define TPG   8       // points per wave per WG
#define NWG   1024
#define GMAX  8191

typedef __bf16 bf16_t;
typedef bf16_t bf16x8 __attribute__((ext_vector_type(8)));
typedef float  f32x4  __attribute__((ext_vector_type(4)));

__device__ __forceinline__ uint32_t pack2bf(float a, float b) {
    union { bf16_t h[2]; uint32_t u; } x;
    x.h[0] = (bf16_t)a; x.h[1] = (bf16_t)b;
    return x.u;
}

// forced-issue global load: volatile asm cannot be sunk/reordered by the scheduler
__device__ __forceinline__ f32x4 gld16(const float* p) {
    f32x4 r;
    asm volatile("global_load_dwordx4 %0, %1, off"
                 : "=v"(r) : "v"(p) : "memory");
    return r;
}
// asm loads are invisible to compiler waitcnt insertion -> explicit drain + fence
#define WAIT_ALL() do { \
    asm volatile("s_waitcnt vmcnt(0)" ::: "memory"); \
    __builtin_amdgcn_sched_barrier(0); } while (0)

template<bool DIRECT>
__global__ __launch_bounds__(256, 2)
void sa_main(const float* __restrict__ dp, const float* __restrict__ fj,
             const float* __restrict__ W1, const float* __restrict__ b1,
             const float* __restrict__ W2, const float* __restrict__ b2,
             float* __restrict__ dst)
{
    // LDS: X staging only (4 waves x 32 k-rows x CSTR). Weights pass through
    // transient overlays of this region during the prologue, then live in regs.
    __shared__ bf16_t smem[4 * 32 * CSTR];   // 26,624 B

    const int tid  = threadIdx.x;
    const int wave = tid >> 6;
    const int lane = tid & 63;
    const int lrow = lane & 15;   // MFMA row/col within 16-tile; kpos pair {2*lrow, 2*lrow+1}
    const int g    = lane >> 4;   // 16-lane group (fragment k-group)

    bf16_t* Xw = smem + wave * 32 * CSTR;

    const size_t plane = (size_t)N_ * K_;
    const int bidx = blockIdx.x;
    const int b    = (bidx * TPG) >> 11;    // batch constant per WG (TPG | 2048)

    const int cr = lane >> 3;            // staging: channel-in-group 0..7
    const int k0 = (lane & 7) << 2;      // staging: k base 0..28

    // ---- slim issuer, now with FORCED-ISSUE asm loads (anti-sinking) ----
    f32x4 v[9];
    auto issue = [&](int Gi) {
        const int bb = Gi >> 11;
        const int nn = ((Gi & 2047) << 2) + wave;
        const size_t rbase = (size_t)nn * K_ + k0;
        const float* fp  = fj + (size_t)bb * 64 * plane + rbase;
        const float* dp0 = dp + (size_t)bb * 3  * plane + rbase;
        const float* p0 = (cr < 3) ? dp0 + (size_t)cr * plane
                                   : fp  + (size_t)(cr - 3) * plane;
        v[0] = gld16(p0);
        const float* pj = fp + (size_t)(8 + cr - 3) * plane;
        #pragma unroll
        for (int j = 1; j < 8; ++j) {
            v[j] = gld16(pj);
            pj += 8 * plane;
        }
        const int c8 = (cr < 3) ? (64 + cr) : 66;   // clamp: line already fetched
        v[8] = gld16(fp + (size_t)(c8 - 3) * plane);
    };

    // t=0 loads in flight across the whole weight prologue
    issue(bidx * TPG);

    // ---- prologue: W1 (PERMUTED rows) via transient overlay -> regs ----
    // slot s=(rt*16+4q+i) holds out-chan pi = 32*(rt>>1)+8q+4*(rt&1)+i
    for (int i = tid; i < 64 * 96; i += 256) {
        int s = i / 96, c = i - s * 96;
        int rt = s >> 4, rr = s & 15, qq = rr >> 2, ii = rr & 3;
        int o = 32 * (rt >> 1) + 8 * qq + 4 * (rt & 1) + ii;
        smem[i] = (c < CX) ? (bf16_t)W1[o * CX + c] : (bf16_t)0.f;
    }
    __syncthreads();
    bf16x8 w1f[3][4];
    #pragma unroll
    for (int kc = 0; kc < 3; ++kc)
        #pragma unroll
        for (int rt = 0; rt < 4; ++rt)
            w1f[kc][rt] = *(const bf16x8*)&smem[(rt * 16 + lrow) * 96 + kc * 32 + g * 8];
    __syncthreads();
    // W2 [out][mid] via transient overlay -> regs (B operand of layer-2 MFMA)
    for (int i = tid; i < 128 * 72; i += 256) {
        int o = i / 72, c = i - o * 72;
        smem[i] = (c < CMID) ? (bf16_t)W2[o * CMID + c] : (bf16_t)0.f;
    }
    __syncthreads();
    bf16x8 w2f[2][8];
    #pragma unroll
    for (int kcc = 0; kcc < 2; ++kcc)
        #pragma unroll
        for (int ot = 0; ot < 8; ++ot)
            w2f[kcc][ot] = *(const bf16x8*)&smem[(ot * 16 + lrow) * 72 + kcc * 32 + g * 8];
    __syncthreads();
    // zero Xs (pad chans 67..103 stay zero FOREVER; 0..66 rewritten each point.
    // kc=2 fragment reads span chans 64..95 -> pads must be exact zero, R8 lesson)
    for (int i = tid; i < 4 * 32 * CSTR; i += 256) smem[i] = (bf16_t)0.f;
    __syncthreads();

    f32x4 b1f[4];   // permuted to match W1 row order
    #pragma unroll
    for (int rt = 0; rt < 4; ++rt)
        b1f[rt] = *(const f32x4*)(b1 + 32 * (rt >> 1) + 8 * g + 4 * (rt & 1));
    float b2f[8];
    #pragma unroll
    for (int ot = 0; ot < 8; ++ot) b2f[ot] = b2[ot * 16 + lrow];

    #pragma unroll 1
    for (int t = 0; t < TPG; ++t) {
        const int G = bidx * TPG + t;
        const int n = ((G & 2047) << 2) + wave;

        // ---- drain this point's loads (issued one full compute-phase ago) ----
        WAIT_ALL();

        // ---- stage current v -> Xw [k][chan] (consumes v; wave-private) ----
        #pragma unroll
        for (int j = 0; j < 9; ++j) {
            int c = j * 8 + cr;
            if (c < CX) {
                Xw[(k0 + 0) * CSTR + c] = (bf16_t)v[j][0];
                Xw[(k0 + 1) * CSTR + c] = (bf16_t)v[j][1];
                Xw[(k0 + 2) * CSTR + c] = (bf16_t)v[j][2];
                Xw[(k0 + 3) * CSTR + c] = (bf16_t)v[j][3];
            }
        }
        // ---- forced-issue loads for next point: in flight across ALL of compute ----
        { int Gn = G + 1; if (Gn > GMAX) Gn = GMAX; issue(Gn); }

        // ---- X B-frags: col s=lrow <- kpos 2s (f0) / 2s+1 (f1); single b128 each ----
        bf16x8 f0[3], f1[3];
        #pragma unroll
        for (int kc = 0; kc < 3; ++kc) {
            f0[kc] = *(const bf16x8*)&Xw[(2 * lrow)     * CSTR + kc * 32 + g * 8];
            f1[kc] = *(const bf16x8*)&Xw[(2 * lrow + 1) * CSTR + kc * 32 + g * 8];
        }

        // ---- layer 1 + epilogue, half 0 (even kpos) then half 1 (odd) ----
        bf16x8 a2f0[2], a2f1[2];
        {
            f32x4 acc[4] = {};
            __builtin_amdgcn_s_setprio(1);
            #pragma unroll
            for (int kc = 0; kc < 3; ++kc)
                #pragma unroll
                for (int rt = 0; rt < 4; ++rt)
                    acc[rt] = __builtin_amdgcn_mfma_f32_16x16x32_bf16(w1f[kc][rt], f0[kc], acc[rt], 0, 0, 0);
            __builtin_amdgcn_s_setprio(0);
            #pragma unroll
            for (int kc2 = 0; kc2 < 2; ++kc2) {
                union { uint32_t u[4]; bf16x8 w; } cc;
                #pragma unroll
                for (int hh = 0; hh < 2; ++hh) {
                    const int rt = 2 * kc2 + hh;
                    float h0 = fmaxf(acc[rt][0] + b1f[rt][0], 0.f);
                    float h1 = fmaxf(acc[rt][1] + b1f[rt][1], 0.f);
                    float h2 = fmaxf(acc[rt][2] + b1f[rt][2], 0.f);
                    float h3 = fmaxf(acc[rt][3] + b1f[rt][3], 0.f);
                    cc.u[hh * 2 + 0] = pack2bf(h0, h1);
                    cc.u[hh * 2 + 1] = pack2bf(h2, h3);
                }
                a2f0[kc2] = cc.w;
            }
        }
        {
            f32x4 acc[4] = {};
            __builtin_amdgcn_s_setprio(1);
            #pragma unroll
            for (int kc = 0; kc < 3; ++kc)
                #pragma unroll
                for (int rt = 0; rt < 4; ++rt)
                    acc[rt] = __builtin_amdgcn_mfma_f32_16x16x32_bf16(w1f[kc][rt], f1[kc], acc[rt], 0, 0, 0);
            __builtin_amdgcn_s_setprio(0);
            #pragma unroll
            for (int kc2 = 0; kc2 < 2; ++kc2) {
                union { uint32_t u[4]; bf16x8 w; } cc;
                #pragma unroll
                for (int hh = 0; hh < 2; ++hh) {
                    const int rt = 2 * kc2 + hh;
                    float h0 = fmaxf(acc[rt][0] + b1f[rt][0], 0.f);
                    float h1 = fmaxf(acc[rt][1] + b1f[rt][1], 0.f);
                    float h2 = fmaxf(acc[rt][2] + b1f[rt][2], 0.f);
                    float h3 = fmaxf(acc[rt][3] + b1f[rt][3], 0.f);
                    cc.u[hh * 2 + 0] = pack2bf(h0, h1);
                    cc.u[hh * 2 + 1] = pack2bf(h2, h3);
                }
                a2f1[kc2] = cc.w;
            }
        }

        // ---- layer 2: A = packed H (regs), B = W2 (regs); D rows = kpos slots ----
        float macc[8];
        __builtin_amdgcn_s_setprio(1);
        #pragma unroll
        for (int ot = 0; ot < 8; ++ot) {
            f32x4 t0 = {}, t1 = {};
            t0 = __builtin_amdgcn_mfma_f32_16x16x32_bf16(a2f0[0], w2f[0][ot], t0, 0, 0, 0);
            t0 = __builtin_amdgcn_mfma_f32_16x16x32_bf16(a2f0[1], w2f[1][ot], t0, 0, 0, 0);
            t1 = __builtin_amdgcn_mfma_f32_16x16x32_bf16(a2f1[0], w2f[0][ot], t1, 0, 0, 0);
            t1 = __builtin_amdgcn_mfma_f32_16x16x32_bf16(a2f1[1], w2f[1][ot], t1, 0, 0, 0);
            float m0 = fmaxf(fmaxf(t0[0], t0[1]), fmaxf(t0[2], t0[3]));
            float m1 = fmaxf(fmaxf(t1[0], t1[1]), fmaxf(t1[2], t1[3]));
            macc[ot] = fmaxf(m0, m1);   // in-lane pool over this lane's 8 kpos
        }
        __builtin_amdgcn_s_setprio(0);

        // ---- cross-group pool (xor16 + xor32), bias, relu ----
        #pragma unroll
        for (int ot = 0; ot < 8; ++ot) {
            float vv = macc[ot];
            vv = fmaxf(vv, __shfl_xor(vv, 16, 64));
            vv = fmaxf(vv, __shfl_xor(vv, 32, 64));
            macc[ot] = fmaxf(vv + b2f[ot], 0.f);
        }
        float oa = (g == 0) ? macc[0] : (g == 1) ? macc[2] : (g == 2) ? macc[4] : macc[6];
        float ob = (g == 0) ? macc[1] : (g == 1) ? macc[3] : (g == 2) ? macc[5] : macc[7];
        const int ca  = g * 32 + lrow;
        const int cb2 = g * 32 + 16 + lrow;
        if (DIRECT) {
            float* op = dst + (size_t)b * COUT * N_ + n;
            op[(size_t)ca  * N_] = oa;
            op[(size_t)cb2 * N_] = ob;
        } else {
            float* wp = dst + ((size_t)(b * N_ + n)) * COUT;   // ws[b][n][c]
            wp[ca]  = oa;
            wp[cb2] = ob;
        }
    }
}

// ws[b][n][c] -> out[b][c][n], full lines on both sides
__global__ __launch_bounds__(256)
void sa_transpose(const float* __restrict__ ws, float* __restrict__ out)
{
    __shared__ float tile[32][136];
    const int t  = threadIdx.x;
    const int i  = blockIdx.x;         // 0..1023
    const int b  = i >> 8;
    const int n0 = (i & 255) << 5;

    const float* rp = ws + ((size_t)(b * N_ + n0)) * COUT;
    #pragma unroll
    for (int r = 0; r < 4; ++r) {
        int flat = (r * 256 + t) * 4;
        int nl = flat >> 7, c = flat & 127;
        float4 v = *(const float4*)(rp + (size_t)nl * COUT + c);
        *(float4*)&tile[nl][c] = v;
    }
    __syncthreads();
    float* op = out + (size_t)b * COUT * N_ + n0;
    const int nl4 = (t & 7) << 2;
    #pragma unroll
    for (int r2 = 0; r2 < 4; ++r2) {
        int c = r2 * 32 + (t >> 3);
        float4 o4;
        o4.x = tile[nl4 + 0][c];
        o4.y = tile[nl4 + 1][c];
        o4.z = tile[nl4 + 2][c];
        o4.w = tile[nl4 + 3][c];
        *(float4*)(op + (size_t)c * N_ + nl4) = o4;
    }
}

extern "C" void kernel_launch(void* const* d_in, const int* in_sizes, int n_in,
                              void* d_out, int out_size, void* d_ws, size_t ws_size,
                              hipStream_t stream) {
    // inputs: 0=p (unused), 1=f (unused), 2=dp, 3=fj, 4=W1, 5=b1, 6=W2, 7=b2
    const float* dp = (const float*)d_in[2];
    const float* fj = (const float*)d_in[3];
    const float* W1 = (const float*)d_in[4];
    const float* b1 = (const float*)d_in[5];
    const float* W2 = (const float*)d_in[6];
    const float* b2 = (const float*)d_in[7];
    float* out = (float*)d_out;

    const size_t ws_need = (size_t)B_ * N_ * COUT * sizeof(float);
    if (ws_size >= ws_need) {
        float* ws = (float*)d_ws;
        hipLaunchKernelGGL((sa_main<false>), dim3(NWG), dim3(256), 0, stream,
                           dp, fj, W1, b1, W2, b2, ws);
        hipLaunchKernelGGL(sa_transpose, dim3(1024), dim3(256), 0, stream, ws, out);
    } else {
        hipLaunchKernelGGL((sa_main<true>), dim3(NWG), dim3(256), 0, stream,
                           dp, fj, W1, b1, W2, b2, out);
    }
}